// Round 8
// baseline (15.922 us; speedup 1.0000x reference)
//
#include <hip/hip_runtime.h>

// dag[i,j] = s[i,j]*nr[j] * (i<j ? 1 : (i>j ? 1 - s[j,i]*nr[i] : 0))
// s[i,j] = (ep[i,j]+ge[i,j,0]) > ((1-ep[i,j])+ge[i,j,1])
// nr[j]  = 1 - ((rp[j]+gr[j,0]) > ((1-rp[j])+gr[j,1]))

typedef float f4 __attribute__((ext_vector_type(4)));

constexpr int TS   = 32;
constexpr int NBLK = 1040;   // 2080 pairs / 2 per block -> perfectly balanced

__device__ __forceinline__ void decode_pair(int p, int& bi, int& bj) {
    int a = (int)((sqrtf(8.0f * (float)p + 1.0f) - 1.0f) * 0.5f);
    while ((a + 1) * (a + 2) / 2 <= p) ++a;
    while (a * (a + 1) / 2 > p) --a;
    bi = p - a * (a + 1) / 2;
    bj = a;
}

__global__ __launch_bounds__(256) void dag_kernel(
    const float*  __restrict__ rp,
    const float2* __restrict__ gr2,
    const float*  __restrict__ ep,
    const f4*     __restrict__ ge4,
    float* __restrict__ out, int n)
{
    __shared__ float Ash0[TS][TS + 1];
    __shared__ float Ash1[TS][TS + 1];
    __shared__ float nrJ0[TS], nrI0[TS], nrJ1[TS], nrI1[TS];

    int bi0, bj0, bi1, bj1;
    decode_pair(blockIdx.x, bi0, bj0);
    decode_pair(blockIdx.x + NBLK, bi1, bj1);
    const int I0 = bi0 * TS, J0 = bj0 * TS;
    const int I1 = bi1 * TS, J1 = bj1 * TS;
    const bool diag0 = (bi0 == bj0), diag1 = (bi1 == bj1);

    const int t   = threadIdx.x;
    const int row = t >> 3;          // 0..31
    const int c4  = (t & 7) << 2;    // 0,4,...,28

    // ---- nr indicators for all 4 column groups (128 threads) ----
    if (t < 4 * TS) {
        const int grp = t >> 5, lane = t & 31;
        const int base = (grp == 0) ? J0 : (grp == 1) ? I0 : (grp == 2) ? J1 : I1;
        const int j = base + lane;
        float pj = rp[j]; float2 g = gr2[j];
        float v = ((pj + g.x) > ((1.0f - pj) + g.y)) ? 0.0f : 1.0f;
        if (grp == 0)      nrJ0[lane] = v;
        else if (grp == 1) nrI0[lane] = v;
        else if (grp == 2) nrJ1[lane] = v;
        else               nrI1[lane] = v;
    }

    // ---- all 12 streaming loads issued at block start (max MLP) ----
    const size_t idxA0 = (size_t)(I0 + row) * n + (size_t)(J0 + c4);
    const size_t idxB0 = (size_t)(J0 + row) * n + (size_t)(I0 + c4);
    const size_t idxA1 = (size_t)(I1 + row) * n + (size_t)(J1 + c4);
    const size_t idxB1 = (size_t)(J1 + row) * n + (size_t)(I1 + c4);

    const f4 epA0 = *(const f4*)(ep + idxA0);
    const f4 qA00 = ge4[idxA0 >> 1];
    const f4 qA01 = ge4[(idxA0 >> 1) + 1];
    const f4 epB0 = *(const f4*)(ep + idxB0);
    const f4 qB00 = ge4[idxB0 >> 1];
    const f4 qB01 = ge4[(idxB0 >> 1) + 1];
    const f4 epA1 = *(const f4*)(ep + idxA1);
    const f4 qA10 = ge4[idxA1 >> 1];
    const f4 qA11 = ge4[(idxA1 >> 1) + 1];
    const f4 epB1 = *(const f4*)(ep + idxB1);
    const f4 qB10 = ge4[idxB1 >> 1];
    const f4 qB11 = ge4[(idxB1 >> 1) + 1];

    // ---- pair 0: tile A samples -> LDS ----
    float sA0[4];
    sA0[0] = ((epA0.x + qA00.x) > ((1.0f - epA0.x) + qA00.y)) ? 1.0f : 0.0f;
    sA0[1] = ((epA0.y + qA00.z) > ((1.0f - epA0.y) + qA00.w)) ? 1.0f : 0.0f;
    sA0[2] = ((epA0.z + qA01.x) > ((1.0f - epA0.z) + qA01.y)) ? 1.0f : 0.0f;
    sA0[3] = ((epA0.w + qA01.z) > ((1.0f - epA0.w) + qA01.w)) ? 1.0f : 0.0f;
    Ash0[row][c4 + 0] = sA0[0];
    Ash0[row][c4 + 1] = sA0[1];
    Ash0[row][c4 + 2] = sA0[2];
    Ash0[row][c4 + 3] = sA0[3];

    // barrier 1: wait only on LDS; pair-1 global loads stay in flight
    asm volatile("s_waitcnt lgkmcnt(0)" ::: "memory");
    __builtin_amdgcn_s_barrier();
    __builtin_amdgcn_sched_barrier(0);

    // ---- pair 0 outputs ----
    if (diag0) {
        const float nr_row = nrJ0[row];
        f4 v;
#pragma unroll
        for (int c = 0; c < 4; ++c) {
            int col = c4 + c;
            float x;
            if (row == col)      x = 0.0f;
            else if (row < col)  x = sA0[c] * nrJ0[col];
            else                 x = sA0[c] * nrJ0[col] * (1.0f - Ash0[col][row] * nr_row);
            v[c] = x;
        }
        *(f4*)(out + idxA0) = v;
    } else {
        f4 u;
        u.x = sA0[0] * nrJ0[c4 + 0];
        u.y = sA0[1] * nrJ0[c4 + 1];
        u.z = sA0[2] * nrJ0[c4 + 2];
        u.w = sA0[3] * nrJ0[c4 + 3];
        *(f4*)(out + idxA0) = u;

        float sB0[4];
        sB0[0] = ((epB0.x + qB00.x) > ((1.0f - epB0.x) + qB00.y)) ? 1.0f : 0.0f;
        sB0[1] = ((epB0.y + qB00.z) > ((1.0f - epB0.y) + qB00.w)) ? 1.0f : 0.0f;
        sB0[2] = ((epB0.z + qB01.x) > ((1.0f - epB0.z) + qB01.y)) ? 1.0f : 0.0f;
        sB0[3] = ((epB0.w + qB01.z) > ((1.0f - epB0.w) + qB01.w)) ? 1.0f : 0.0f;

        const float nr_row = nrJ0[row];
        f4 w;
        w.x = sB0[0] * nrI0[c4 + 0] * (1.0f - Ash0[c4 + 0][row] * nr_row);
        w.y = sB0[1] * nrI0[c4 + 1] * (1.0f - Ash0[c4 + 1][row] * nr_row);
        w.z = sB0[2] * nrI0[c4 + 2] * (1.0f - Ash0[c4 + 2][row] * nr_row);
        w.w = sB0[3] * nrI0[c4 + 3] * (1.0f - Ash0[c4 + 3][row] * nr_row);
        *(f4*)(out + idxB0) = w;
    }

    // ---- pair 1: tile A samples -> LDS (loads have been in flight all along) ----
    float sA1[4];
    sA1[0] = ((epA1.x + qA10.x) > ((1.0f - epA1.x) + qA10.y)) ? 1.0f : 0.0f;
    sA1[1] = ((epA1.y + qA10.z) > ((1.0f - epA1.y) + qA10.w)) ? 1.0f : 0.0f;
    sA1[2] = ((epA1.z + qA11.x) > ((1.0f - epA1.z) + qA11.y)) ? 1.0f : 0.0f;
    sA1[3] = ((epA1.w + qA11.z) > ((1.0f - epA1.w) + qA11.w)) ? 1.0f : 0.0f;
    Ash1[row][c4 + 0] = sA1[0];
    Ash1[row][c4 + 1] = sA1[1];
    Ash1[row][c4 + 2] = sA1[2];
    Ash1[row][c4 + 3] = sA1[3];

    // barrier 2: again LDS-only wait
    asm volatile("s_waitcnt lgkmcnt(0)" ::: "memory");
    __builtin_amdgcn_s_barrier();
    __builtin_amdgcn_sched_barrier(0);

    // ---- pair 1 outputs ----
    if (diag1) {
        const float nr_row = nrJ1[row];
        f4 v;
#pragma unroll
        for (int c = 0; c < 4; ++c) {
            int col = c4 + c;
            float x;
            if (row == col)      x = 0.0f;
            else if (row < col)  x = sA1[c] * nrJ1[col];
            else                 x = sA1[c] * nrJ1[col] * (1.0f - Ash1[col][row] * nr_row);
            v[c] = x;
        }
        *(f4*)(out + idxA1) = v;
    } else {
        f4 u;
        u.x = sA1[0] * nrJ1[c4 + 0];
        u.y = sA1[1] * nrJ1[c4 + 1];
        u.z = sA1[2] * nrJ1[c4 + 2];
        u.w = sA1[3] * nrJ1[c4 + 3];
        *(f4*)(out + idxA1) = u;

        float sB1[4];
        sB1[0] = ((epB1.x + qB10.x) > ((1.0f - epB1.x) + qB10.y)) ? 1.0f : 0.0f;
        sB1[1] = ((epB1.y + qB10.z) > ((1.0f - epB1.y) + qB10.w)) ? 1.0f : 0.0f;
        sB1[2] = ((epB1.z + qB11.x) > ((1.0f - epB1.z) + qB11.y)) ? 1.0f : 0.0f;
        sB1[3] = ((epB1.w + qB11.z) > ((1.0f - epB1.w) + qB11.w)) ? 1.0f : 0.0f;

        const float nr_row = nrJ1[row];
        f4 w;
        w.x = sB1[0] * nrI1[c4 + 0] * (1.0f - Ash1[c4 + 0][row] * nr_row);
        w.y = sB1[1] * nrI1[c4 + 1] * (1.0f - Ash1[c4 + 1][row] * nr_row);
        w.z = sB1[2] * nrI1[c4 + 2] * (1.0f - Ash1[c4 + 2][row] * nr_row);
        w.w = sB1[3] * nrI1[c4 + 3] * (1.0f - Ash1[c4 + 3][row] * nr_row);
        *(f4*)(out + idxB1) = w;
    }
}

extern "C" void kernel_launch(void* const* d_in, const int* in_sizes, int n_in,
                              void* d_out, int out_size, void* d_ws, size_t ws_size,
                              hipStream_t stream) {
    const float*  rp = (const float*)d_in[0];   // root_probs (N)
    const float*  ep = (const float*)d_in[1];   // edge_probs (N,N)
    const float2* gr = (const float2*)d_in[2];  // g_root (N,2)
    const f4*     ge = (const f4*)d_in[3];      // g_edge (N,N,2) as f4
    float* out = (float*)d_out;
    const int n = in_sizes[0];

    // 64 tile-bands -> 2080 pairs -> 1040 blocks x 2 pipelined pairs (balanced)
    dag_kernel<<<NBLK, 256, 0, stream>>>(rp, gr, ep, ge, out, n);
}

// Round 9
// 15.398 us; speedup vs baseline: 1.0341x; 1.0341x over previous
//
#include <hip/hip_runtime.h>

// dag[i,j] = s[i,j]*nr[j] * (i<j ? 1 : (i>j ? 1 - s[j,i]*nr[i] : 0))
// s[i,j] = (ep[i,j]+ge[i,j,0]) > ((1-ep[i,j])+ge[i,j,1])
// nr[j]  = 1 - ((rp[j]+gr[j,0]) > ((1-rp[j])+gr[j,1]))

typedef float f4 __attribute__((ext_vector_type(4)));

constexpr int TS   = 32;     // 32x32 tiles
constexpr int NB   = 64;     // 2048/32 bands
constexpr int NOFF = NB * (NB - 1) / 2;   // 2016 off-diag pairs (scheduled first)

__global__ __launch_bounds__(256) void dag_kernel(
    const float*  __restrict__ rp,
    const float2* __restrict__ gr2,
    const float*  __restrict__ ep,
    const f4*     __restrict__ ge4,
    float* __restrict__ out, int n)
{
    __shared__ float Ash[TS][TS + 1];  // raw sample s of tile A; +1 pad
    __shared__ float nrJ[TS];          // nr for cols J..J+31
    __shared__ float nrI[TS];          // nr for cols I..I+31

    // pair decode, diag pairs LAST (blockIdx >= NOFF) so the straggler
    // round past the ~2048 co-resident blocks is all half-cost diag blocks
    int bi, bj;
    {
        const int p = blockIdx.x;
        if (p < NOFF) {                 // strict lower pairs (bi < bj)
            int b = (int)((1.0f + sqrtf(8.0f * (float)p + 1.0f)) * 0.5f);
            while (b * (b - 1) / 2 > p) --b;
            while ((b + 1) * b / 2 <= p) ++b;
            bj = b;
            bi = p - b * (b - 1) / 2;
        } else {                        // diagonal pairs
            bi = bj = p - NOFF;
        }
    }
    const int I = bi * TS, J = bj * TS;
    const bool diag = (bi == bj);

    const int t   = threadIdx.x;
    const int row = t >> 3;          // 0..31
    const int c4  = (t & 7) << 2;    // 0,4,...,28

    // ---- small nr loads first (they feed the barrier) ----
    float nr_val = 0.0f;
    if (t < 2 * TS) {
        int j = (t < TS) ? (J + t) : (I + (t - TS));
        float pj = rp[j]; float2 g = gr2[j];
        nr_val = ((pj + g.x) > ((1.0f - pj) + g.y)) ? 0.0f : 1.0f;
    }

    // ---- streaming loads: A-tile (pre-barrier), then B-tile (post-barrier use) ----
    const size_t idxA = (size_t)(I + row) * n + (size_t)(J + c4);
    const size_t idxB = (size_t)(J + row) * n + (size_t)(I + c4);
    const f4 epA = *(const f4*)(ep + idxA);
    const f4 qA0 = ge4[idxA >> 1];
    const f4 qA1 = ge4[(idxA >> 1) + 1];
    f4 epB, qB0, qB1;
    if (!diag) {
        epB = *(const f4*)(ep + idxB);
        qB0 = ge4[idxB >> 1];
        qB1 = ge4[(idxB >> 1) + 1];
    }

    if (t < TS)           nrJ[t] = nr_val;
    else if (t < 2 * TS)  nrI[t - TS] = nr_val;

    // ---- tile A raw samples -> LDS ----
    float sA[4];
    sA[0] = ((epA.x + qA0.x) > ((1.0f - epA.x) + qA0.y)) ? 1.0f : 0.0f;
    sA[1] = ((epA.y + qA0.z) > ((1.0f - epA.y) + qA0.w)) ? 1.0f : 0.0f;
    sA[2] = ((epA.z + qA1.x) > ((1.0f - epA.z) + qA1.y)) ? 1.0f : 0.0f;
    sA[3] = ((epA.w + qA1.z) > ((1.0f - epA.w) + qA1.w)) ? 1.0f : 0.0f;
    Ash[row][c4 + 0] = sA[0];
    Ash[row][c4 + 1] = sA[1];
    Ash[row][c4 + 2] = sA[2];
    Ash[row][c4 + 3] = sA[3];

    // ---- barrier that waits ONLY on LDS (B-tile global loads stay in flight) ----
    asm volatile("s_waitcnt lgkmcnt(0)" ::: "memory");
    __builtin_amdgcn_s_barrier();
    __builtin_amdgcn_sched_barrier(0);   // keep post-barrier LDS reads below the barrier

    if (diag) {
        const float nr_row = nrJ[row];
        f4 v;
#pragma unroll
        for (int c = 0; c < 4; ++c) {
            int col = c4 + c;
            float x;
            if (row == col)      x = 0.0f;
            else if (row < col)  x = sA[c] * nrJ[col];
            else                 x = sA[c] * nrJ[col] * (1.0f - Ash[col][row] * nr_row);
            v[c] = x;
        }
        *(f4*)(out + idxA) = v;
    } else {
        // upper tile: i = I+row < j = J+col always (B loads still landing here)
        f4 u;
        u.x = sA[0] * nrJ[c4 + 0];
        u.y = sA[1] * nrJ[c4 + 1];
        u.z = sA[2] * nrJ[c4 + 2];
        u.w = sA[3] * nrJ[c4 + 3];
        *(f4*)(out + idxA) = u;

        // tile B samples (compiler waits on B loads exactly here)
        float sB[4];
        sB[0] = ((epB.x + qB0.x) > ((1.0f - epB.x) + qB0.y)) ? 1.0f : 0.0f;
        sB[1] = ((epB.y + qB0.z) > ((1.0f - epB.y) + qB0.w)) ? 1.0f : 0.0f;
        sB[2] = ((epB.z + qB1.x) > ((1.0f - epB.z) + qB1.y)) ? 1.0f : 0.0f;
        sB[3] = ((epB.w + qB1.z) > ((1.0f - epB.w) + qB1.w)) ? 1.0f : 0.0f;

        // lower tile: i = J+row > j = I+col
        const float nr_row = nrJ[row];   // nr[i], i = J+row
        f4 w;
        w.x = sB[0] * nrI[c4 + 0] * (1.0f - Ash[c4 + 0][row] * nr_row);
        w.y = sB[1] * nrI[c4 + 1] * (1.0f - Ash[c4 + 1][row] * nr_row);
        w.z = sB[2] * nrI[c4 + 2] * (1.0f - Ash[c4 + 2][row] * nr_row);
        w.w = sB[3] * nrI[c4 + 3] * (1.0f - Ash[c4 + 3][row] * nr_row);
        *(f4*)(out + idxB) = w;
    }
}

extern "C" void kernel_launch(void* const* d_in, const int* in_sizes, int n_in,
                              void* d_out, int out_size, void* d_ws, size_t ws_size,
                              hipStream_t stream) {
    const float*  rp = (const float*)d_in[0];   // root_probs (N)
    const float*  ep = (const float*)d_in[1];   // edge_probs (N,N)
    const float2* gr = (const float2*)d_in[2];  // g_root (N,2)
    const f4*     ge = (const f4*)d_in[3];      // g_edge (N,N,2) as f4
    float* out = (float*)d_out;
    const int n = in_sizes[0];

    const int pairs = NOFF + NB;                // 2016 off-diag + 64 diag = 2080
    dag_kernel<<<pairs, 256, 0, stream>>>(rp, gr, ep, ge, out, n);
}

// Round 10
// 14.969 us; speedup vs baseline: 1.0637x; 1.0286x over previous
//
#include <hip/hip_runtime.h>

// dag[i,j] = s[i,j]*nr[j] * (i<j ? 1 : (i>j ? 1 - s[j,i]*nr[i] : 0))
// s[i,j] = (ep[i,j]+ge[i,j,0]) > ((1-ep[i,j])+ge[i,j,1])
// nr[j]  = 1 - ((rp[j]+gr[j,0]) > ((1-rp[j])+gr[j,1]))

typedef float f4 __attribute__((ext_vector_type(4)));

constexpr int TS = 32;   // 32x32 tiles, 2080 blocks

__global__ __launch_bounds__(256) void dag_kernel(
    const float*  __restrict__ rp,
    const float2* __restrict__ gr2,
    const float*  __restrict__ ep,
    const f4*     __restrict__ ge4,
    float* __restrict__ out, int n)
{
    __shared__ float Ash[TS][TS + 1];  // raw sample s of tile A; +1 pad
    __shared__ float nrJ[TS];          // nr for cols J..J+31
    __shared__ float nrI[TS];          // nr for cols I..I+31

    // triangular pair decode: (bi,bj), bi <= bj
    int p = blockIdx.x;
    int a = (int)((sqrtf(8.0f * (float)p + 1.0f) - 1.0f) * 0.5f);
    while ((a + 1) * (a + 2) / 2 <= p) ++a;
    while (a * (a + 1) / 2 > p) --a;
    const int bi = p - a * (a + 1) / 2;
    const int bj = a;
    const int I = bi * TS, J = bj * TS;
    const bool diag = (bi == bj);

    const int t   = threadIdx.x;
    const int row = t >> 3;          // 0..31
    const int c4  = (t & 7) << 2;    // 0,4,...,28

    // ---- small nr loads first (they feed the barrier) ----
    float nr_val = 0.0f;
    if (t < 2 * TS) {
        int j = (t < TS) ? (J + t) : (I + (t - TS));
        float pj = rp[j]; float2 g = gr2[j];
        nr_val = ((pj + g.x) > ((1.0f - pj) + g.y)) ? 0.0f : 1.0f;
    }

    // ---- streaming loads: A-tile (pre-barrier), then B-tile (post-barrier use) ----
    const size_t idxA = (size_t)(I + row) * n + (size_t)(J + c4);
    const size_t idxB = (size_t)(J + row) * n + (size_t)(I + c4);
    const f4 epA = *(const f4*)(ep + idxA);
    const f4 qA0 = ge4[idxA >> 1];
    const f4 qA1 = ge4[(idxA >> 1) + 1];
    f4 epB, qB0, qB1;
    if (!diag) {
        epB = *(const f4*)(ep + idxB);
        qB0 = ge4[idxB >> 1];
        qB1 = ge4[(idxB >> 1) + 1];
    }

    if (t < TS)           nrJ[t] = nr_val;
    else if (t < 2 * TS)  nrI[t - TS] = nr_val;

    // ---- tile A raw samples -> LDS ----
    float sA[4];
    sA[0] = ((epA.x + qA0.x) > ((1.0f - epA.x) + qA0.y)) ? 1.0f : 0.0f;
    sA[1] = ((epA.y + qA0.z) > ((1.0f - epA.y) + qA0.w)) ? 1.0f : 0.0f;
    sA[2] = ((epA.z + qA1.x) > ((1.0f - epA.z) + qA1.y)) ? 1.0f : 0.0f;
    sA[3] = ((epA.w + qA1.z) > ((1.0f - epA.w) + qA1.w)) ? 1.0f : 0.0f;
    Ash[row][c4 + 0] = sA[0];
    Ash[row][c4 + 1] = sA[1];
    Ash[row][c4 + 2] = sA[2];
    Ash[row][c4 + 3] = sA[3];

    // ---- barrier that waits ONLY on LDS (B-tile global loads stay in flight) ----
    asm volatile("s_waitcnt lgkmcnt(0)" ::: "memory");
    __builtin_amdgcn_s_barrier();
    __builtin_amdgcn_sched_barrier(0);   // keep post-barrier LDS reads below the barrier

    if (diag) {
        const float nr_row = nrJ[row];
        f4 v;
#pragma unroll
        for (int c = 0; c < 4; ++c) {
            int col = c4 + c;
            float x;
            if (row == col)      x = 0.0f;
            else if (row < col)  x = sA[c] * nrJ[col];
            else                 x = sA[c] * nrJ[col] * (1.0f - Ash[col][row] * nr_row);
            v[c] = x;
        }
        *(f4*)(out + idxA) = v;
    } else {
        // upper tile: i = I+row < j = J+col always (B loads still landing here)
        f4 u;
        u.x = sA[0] * nrJ[c4 + 0];
        u.y = sA[1] * nrJ[c4 + 1];
        u.z = sA[2] * nrJ[c4 + 2];
        u.w = sA[3] * nrJ[c4 + 3];
        *(f4*)(out + idxA) = u;

        // tile B samples (compiler waits on B loads exactly here)
        float sB[4];
        sB[0] = ((epB.x + qB0.x) > ((1.0f - epB.x) + qB0.y)) ? 1.0f : 0.0f;
        sB[1] = ((epB.y + qB0.z) > ((1.0f - epB.y) + qB0.w)) ? 1.0f : 0.0f;
        sB[2] = ((epB.z + qB1.x) > ((1.0f - epB.z) + qB1.y)) ? 1.0f : 0.0f;
        sB[3] = ((epB.w + qB1.z) > ((1.0f - epB.w) + qB1.w)) ? 1.0f : 0.0f;

        // lower tile: i = J+row > j = I+col
        const float nr_row = nrJ[row];   // nr[i], i = J+row
        f4 w;
        w.x = sB[0] * nrI[c4 + 0] * (1.0f - Ash[c4 + 0][row] * nr_row);
        w.y = sB[1] * nrI[c4 + 1] * (1.0f - Ash[c4 + 1][row] * nr_row);
        w.z = sB[2] * nrI[c4 + 2] * (1.0f - Ash[c4 + 2][row] * nr_row);
        w.w = sB[3] * nrI[c4 + 3] * (1.0f - Ash[c4 + 3][row] * nr_row);
        *(f4*)(out + idxB) = w;
    }
}

extern "C" void kernel_launch(void* const* d_in, const int* in_sizes, int n_in,
                              void* d_out, int out_size, void* d_ws, size_t ws_size,
                              hipStream_t stream) {
    const float*  rp = (const float*)d_in[0];   // root_probs (N)
    const float*  ep = (const float*)d_in[1];   // edge_probs (N,N)
    const float2* gr = (const float2*)d_in[2];  // g_root (N,2)
    const f4*     ge = (const f4*)d_in[3];      // g_edge (N,N,2) as f4
    float* out = (float*)d_out;
    const int n = in_sizes[0];

    const int nb = n / TS;                      // 2048/32 = 64
    const int pairs = nb * (nb + 1) / 2;        // 2080 blocks
    dag_kernel<<<pairs, 256, 0, stream>>>(rp, gr, ep, ge, out, n);
}